// Round 7
// baseline (470.316 us; speedup 1.0000x reference)
//
#include <hip/hip_runtime.h>

#define N_TOK 65536
#define D 64
#define C_CODES 2048
#define DECAYF 0.8f
#define OMDF 0.2f
#define EPSF 1e-5f
#define NCHUNK 4
#define CHUNK (C_CODES / NCHUNK)
#define TC 8                   // codes per register tile
#define NTILE (CHUNK / TC)     // tiles per chunk
#define SEG 16                 // sorted positions per wave in seg_sum

// output layout (floats), concatenated in reference return order
#define OUT_QUANT 0
#define OUT_IND   (N_TOK * D)               // 4194304
#define OUT_EMB   (OUT_IND + N_TOK)         // 4259840
#define OUT_CS    (OUT_EMB + C_CODES * D)   // 4390912
#define OUT_EAVG  (OUT_CS + C_CODES)        // 4392960

// Fused: e2[c] (EXACT same chains as the validated e2_kernel) + tile-transpose
// eTt[t][k][cj] = emb[(t*8+cj)*64 + k]  (per-tile 2KB contiguous blocks so the
// dist kernel's scalar stream is sequential).
__global__ void prep_kernel(const float* __restrict__ emb, float* __restrict__ e2,
                            float* __restrict__ eTt) {
    int c = blockIdx.x * blockDim.x + threadIdx.x;
    const float4* er = (const float4*)(emb + (size_t)c * D);
    float* dst = eTt + (size_t)(c >> 3) * (D * TC) + (c & 7);
    float s0 = 0.f, s1 = 0.f, s2 = 0.f, s3 = 0.f;
#pragma unroll
    for (int i = 0; i < D / 4; ++i) {
        float4 e = er[i];
        s0 = fmaf(e.x, e.x, s0);
        s1 = fmaf(e.y, e.y, s1);
        s2 = fmaf(e.z, e.z, s2);
        s3 = fmaf(e.w, e.w, s3);
        dst[(4 * i + 0) * TC] = e.x;
        dst[(4 * i + 1) * TC] = e.y;
        dst[(4 * i + 2) * TC] = e.z;
        dst[(4 * i + 3) * TC] = e.w;
    }
    e2[c] = (s0 + s1) + (s2 + s3);
}

// Code-tiled distance argmin. Per (token, code) the accumulation is
// BIT-IDENTICAL to the validated R3-R6 kernel: chain a{j}[cc] accumulates
// k = 4i+j in increasing i via fmaf(x_comp, e_val, acc) — exactly d0..d3;
// combine (a0+a1)+(a2+a3); dist2 = x2 + e2[c] - 2*dot; clip; u64-key min in
// increasing c. Only operand residency changed: x is re-fetched once per
// 8-code tile (1 VMEM : 32 FMA, vs R6's 1:4 remat pathology), e comes from
// the wave-uniform eTt stream (s_load -> SGPR fmac operand).
__global__ __launch_bounds__(256) void dist_kernel(
        const float* __restrict__ x, const float* __restrict__ eTt,
        const float* __restrict__ e2, unsigned long long* __restrict__ keys) {
    int token = blockIdx.x * blockDim.x + threadIdx.x;
    int chunk = blockIdx.y;
    const float4* xr = (const float4*)(x + (size_t)token * D);

    float s0 = 0.f, s1 = 0.f, s2 = 0.f, s3 = 0.f;
#pragma unroll
    for (int i = 0; i < D / 4; ++i) {
        float4 xq = xr[i];
        s0 = fmaf(xq.x, xq.x, s0);
        s1 = fmaf(xq.y, xq.y, s1);
        s2 = fmaf(xq.z, xq.z, s2);
        s3 = fmaf(xq.w, xq.w, s3);
    }
    float x2 = (s0 + s1) + (s2 + s3);

    unsigned long long best = ~0ull;
    int t0 = chunk * NTILE;
    for (int t = t0; t < t0 + NTILE; ++t) {
        const float* et = eTt + (size_t)t * (D * TC);
        const float* e2p = e2 + t * TC;
        float a0[TC], a1[TC], a2[TC], a3[TC];
#pragma unroll
        for (int cc = 0; cc < TC; ++cc) { a0[cc] = 0.f; a1[cc] = 0.f; a2[cc] = 0.f; a3[cc] = 0.f; }
#pragma unroll
        for (int i = 0; i < D / 4; ++i) {
            float4 xq = xr[i];
#pragma unroll
            for (int cc = 0; cc < TC; ++cc) {
                a0[cc] = fmaf(xq.x, et[(4 * i + 0) * TC + cc], a0[cc]);
                a1[cc] = fmaf(xq.y, et[(4 * i + 1) * TC + cc], a1[cc]);
                a2[cc] = fmaf(xq.z, et[(4 * i + 2) * TC + cc], a2[cc]);
                a3[cc] = fmaf(xq.w, et[(4 * i + 3) * TC + cc], a3[cc]);
            }
        }
#pragma unroll
        for (int cc = 0; cc < TC; ++cc) {
            float dot = (a0[cc] + a1[cc]) + (a2[cc] + a3[cc]);
            float dist2 = x2 + e2p[cc] - 2.0f * dot;
            dist2 = fmaxf(dist2, 0.0f);
            unsigned long long key =
                ((unsigned long long)__float_as_uint(dist2) << 32) |
                (unsigned int)(t * TC + cc);
            best = key < best ? key : best;
        }
    }
    keys[(size_t)chunk * N_TOK + token] = best;
}

__global__ void finalize_kernel(const unsigned long long* __restrict__ keys,
                                int* __restrict__ idx, float* __restrict__ out,
                                float* __restrict__ counts) {
    __shared__ float lcount[C_CODES];
    for (int i = threadIdx.x; i < C_CODES; i += blockDim.x) lcount[i] = 0.0f;
    __syncthreads();
    int n = blockIdx.x * blockDim.x + threadIdx.x;
    unsigned long long best = keys[n];
#pragma unroll
    for (int j = 1; j < NCHUNK; ++j) {
        unsigned long long k = keys[(size_t)j * N_TOK + n];
        best = k < best ? k : best;
    }
    int c = (int)(best & 0xffffffffull);
    idx[n] = c;
    out[OUT_IND + n] = (float)c;
    atomicAdd(&lcount[c], 1.0f);
    __syncthreads();
    for (int i = threadIdx.x; i < C_CODES; i += blockDim.x) {
        float v = lcount[i];
        if (v != 0.0f) atomicAdd(&counts[i], v);
    }
}

// quantize gather: 16 threads per token, one float4 each.
__global__ void gather_kernel(const float* __restrict__ emb,
                              const int* __restrict__ idx,
                              float* __restrict__ out) {
    int g = blockIdx.x * blockDim.x + threadIdx.x;  // [0, N_TOK*16)
    int n = g >> 4;
    int j = g & 15;
    int c = idx[n];
    float4 e = ((const float4*)emb)[c * (D / 4) + j];
    ((float4*)(out + OUT_QUANT))[g] = e;
}

// Single block: EMA cluster-size + laplace smoothing + exclusive prefix sum.
__global__ void prefix_ema_kernel(const float* __restrict__ counts,
                                  const float* __restrict__ cluster_size,
                                  float* __restrict__ out,
                                  float* __restrict__ smoothed,
                                  int* __restrict__ cursor) {
    __shared__ float scan[256];
    __shared__ float red[256];
    int t = threadIdx.x;
    int base = t * 8;
    float cnt[8], ncs[8];
    float csum = 0.f, nsum = 0.f;
#pragma unroll
    for (int j = 0; j < 8; ++j) {
        cnt[j] = counts[base + j];
        csum += cnt[j];
        ncs[j] = cluster_size[base + j] * DECAYF + cnt[j] * OMDF;
        nsum += ncs[j];
        out[OUT_CS + base + j] = ncs[j];
    }
    scan[t] = csum;
    red[t] = nsum;
    __syncthreads();
    for (int s = 1; s < 256; s <<= 1) {
        float v = scan[t];
        float w = (t >= s) ? scan[t - s] : 0.f;
        __syncthreads();
        scan[t] = v + w;
        __syncthreads();
    }
    for (int s = 128; s > 0; s >>= 1) {
        if (t < s) red[t] += red[t + s];
        __syncthreads();
    }
    float tot = red[0];
    float run = (t == 0) ? 0.f : scan[t - 1];
#pragma unroll
    for (int j = 0; j < 8; ++j) {
        cursor[base + j] = (int)run;  // counts are small ints in float: exact
        run += cnt[j];
        smoothed[base + j] = (ncs[j] + EPSF) / (tot + (float)C_CODES * EPSF) * tot;
    }
}

// counting-sort position scatter; entry packs (code<<16 | token) so the
// segmented-sum pass needs only ONE load per position.
__global__ void scatter_pos_kernel(const int* __restrict__ idx,
                                   int* __restrict__ cursor,
                                   unsigned int* __restrict__ sorted) {
    int n = blockIdx.x * blockDim.x + threadIdx.x;
    int c = idx[n];
    int pos = atomicAdd(&cursor[c], 1);
    sorted[pos] = ((unsigned int)c << 16) | (unsigned int)n;
}

// Segmented sum over sorted positions: each wave owns SEG contiguous entries
// (skew-immune), loads all SEG x-rows with independent in-flight loads, and
// flushes one 64-lane atomicAdd per code-run boundary (~0.4M atomics total).
__global__ __launch_bounds__(256) void seg_sum_kernel(
        const float* __restrict__ x, const unsigned int* __restrict__ sorted,
        float* __restrict__ embed_sum) {
    int lane = threadIdx.x & 63;
    int q = blockIdx.x * 4 + (threadIdx.x >> 6);  // wave id
    int p0 = q * SEG;

    unsigned int mine = (lane < SEG) ? sorted[p0 + lane] : 0u;
    unsigned int pk[SEG];
#pragma unroll
    for (int j = 0; j < SEG; ++j) pk[j] = __shfl(mine, j, 64);

    float xv[SEG];
#pragma unroll
    for (int j = 0; j < SEG; ++j)
        xv[j] = x[(size_t)(pk[j] & 0xffffu) * D + lane];  // 16 independent loads

    unsigned int run_c = 0xffffffffu;
    float sum = 0.f;
#pragma unroll
    for (int j = 0; j < SEG; ++j) {
        unsigned int c = pk[j] >> 16;  // wave-uniform
        if (c != run_c) {
            if (run_c != 0xffffffffu)
                atomicAdd(&embed_sum[(size_t)run_c * D + lane], sum);
            run_c = c;
            sum = 0.f;
        }
        sum += xv[j];
    }
    atomicAdd(&embed_sum[(size_t)run_c * D + lane], sum);
}

__global__ void ema_embed_kernel(const float* __restrict__ embed_avg,
                                 const float* __restrict__ embed_sum,
                                 const float* __restrict__ smoothed,
                                 float* __restrict__ out) {
    int g = blockIdx.x * blockDim.x + threadIdx.x;  // [0, C_CODES*16)
    int c = g >> 4;
    float4 ea = ((const float4*)embed_avg)[g];
    float4 es = ((const float4*)embed_sum)[g];
    float4 na;
    na.x = ea.x * DECAYF + es.x * OMDF;
    na.y = ea.y * DECAYF + es.y * OMDF;
    na.z = ea.z * DECAYF + es.z * OMDF;
    na.w = ea.w * DECAYF + es.w * OMDF;
    ((float4*)(out + OUT_EAVG))[g] = na;
    float sm = smoothed[c];
    float4 ne;
    ne.x = na.x / sm;
    ne.y = na.y / sm;
    ne.z = na.z / sm;
    ne.w = na.w / sm;
    ((float4*)(out + OUT_EMB))[g] = ne;
}

extern "C" void kernel_launch(void* const* d_in, const int* in_sizes, int n_in,
                              void* d_out, int out_size, void* d_ws, size_t ws_size,
                              hipStream_t stream) {
    const float* x            = (const float*)d_in[0];  // (16,4096,64)
    const float* emb          = (const float*)d_in[1];  // (1,2048,64)
    const float* cluster_size = (const float*)d_in[2];  // (1,2048)
    const float* embed_avg    = (const float*)d_in[3];  // (1,2048,64)
    float* out = (float*)d_out;

    // workspace layout (keys first for 8B alignment)
    unsigned long long* keys = (unsigned long long*)d_ws;       // 4*65536 u64 = 2 MB
    float* eTt       = (float*)(keys + (size_t)NCHUNK * N_TOK); // 64*2048 = 512 KB
    float* e2        = eTt + (size_t)D * C_CODES;               // 2048
    float* counts    = e2 + C_CODES;                            // 2048 (zeroed)
    float* smoothed  = counts + C_CODES;                        // 2048
    int* cursor      = (int*)(smoothed + C_CODES);              // 2048
    int* idx         = cursor + C_CODES;                        // 65536
    unsigned int* sorted = (unsigned int*)(idx + N_TOK);        // 65536
    float* embed_sum = (float*)(sorted + N_TOK);                // 131072 (zeroed)

    hipMemsetAsync(counts, 0, C_CODES * sizeof(float), stream);
    hipMemsetAsync(embed_sum, 0, (size_t)C_CODES * D * sizeof(float), stream);

    prep_kernel<<<C_CODES / 256, 256, 0, stream>>>(emb, e2, eTt);
    dist_kernel<<<dim3(N_TOK / 256, NCHUNK), 256, 0, stream>>>(x, eTt, e2, keys);
    finalize_kernel<<<N_TOK / 256, 256, 0, stream>>>(keys, idx, out, counts);
    gather_kernel<<<(N_TOK * 16) / 256, 256, 0, stream>>>(emb, idx, out);
    prefix_ema_kernel<<<1, 256, 0, stream>>>(counts, cluster_size, out, smoothed, cursor);
    scatter_pos_kernel<<<N_TOK / 256, 256, 0, stream>>>(idx, cursor, sorted);
    seg_sum_kernel<<<(N_TOK / SEG) / 4, 256, 0, stream>>>(x, sorted, embed_sum);
    ema_embed_kernel<<<(C_CODES * 16) / 256, 256, 0, stream>>>(embed_avg, embed_sum,
                                                              smoothed, out);
}

// Round 8
// 447.939 us; speedup vs baseline: 1.0500x; 1.0500x over previous
//
#include <hip/hip_runtime.h>

#define N_TOK 65536
#define D 64
#define C_CODES 2048
#define DECAYF 0.8f
#define OMDF 0.2f
#define EPSF 1e-5f
#define SEG 16                 // sorted positions per wave in seg_sum

// output layout (floats), concatenated in reference return order
#define OUT_QUANT 0
#define OUT_IND   (N_TOK * D)               // 4194304
#define OUT_EMB   (OUT_IND + N_TOK)         // 4259840
#define OUT_CS    (OUT_EMB + C_CODES * D)   // 4390912
#define OUT_EAVG  (OUT_CS + C_CODES)        // 4392960

typedef short bf16x8 __attribute__((ext_vector_type(8)));
typedef float f32x4 __attribute__((ext_vector_type(4)));
typedef _Float16 h8 __attribute__((ext_vector_type(8)));

static __device__ __forceinline__ unsigned short f2bf(float f) {
    unsigned int u = __float_as_uint(f);
    unsigned int r = u + 0x7fffu + ((u >> 16) & 1u);  // RNE
    return (unsigned short)(r >> 16);
}

// exact e2 (validated chains) + bf16 row conversion + max(e2) for margin
__global__ void prep_e_kernel(const float* __restrict__ emb, float* __restrict__ e2,
                              unsigned short* __restrict__ e_bf,
                              unsigned int* __restrict__ maxe2bits) {
    int c = blockIdx.x * blockDim.x + threadIdx.x;
    const float4* er = (const float4*)(emb + (size_t)c * D);
    unsigned short* dst = e_bf + (size_t)c * D;
    float s0 = 0.f, s1 = 0.f, s2 = 0.f, s3 = 0.f;
#pragma unroll
    for (int i = 0; i < D / 4; ++i) {
        float4 e = er[i];
        s0 = fmaf(e.x, e.x, s0);
        s1 = fmaf(e.y, e.y, s1);
        s2 = fmaf(e.z, e.z, s2);
        s3 = fmaf(e.w, e.w, s3);
        dst[4 * i + 0] = f2bf(e.x);
        dst[4 * i + 1] = f2bf(e.y);
        dst[4 * i + 2] = f2bf(e.z);
        dst[4 * i + 3] = f2bf(e.w);
    }
    float v = (s0 + s1) + (s2 + s3);
    e2[c] = v;
    atomicMax(maxe2bits, __float_as_uint(v));  // e2 > 0: uint order == float order
}

// exact x2 per token (chains identical to validated dist preamble)
__global__ void prep_x2_kernel(const float* __restrict__ x, float* __restrict__ x2) {
    int n = blockIdx.x * blockDim.x + threadIdx.x;
    const float4* xr = (const float4*)(x + (size_t)n * D);
    float s0 = 0.f, s1 = 0.f, s2 = 0.f, s3 = 0.f;
#pragma unroll
    for (int i = 0; i < D / 4; ++i) {
        float4 xq = xr[i];
        s0 = fmaf(xq.x, xq.x, s0);
        s1 = fmaf(xq.y, xq.y, s1);
        s2 = fmaf(xq.z, xq.z, s2);
        s3 = fmaf(xq.w, xq.w, s3);
    }
    x2[n] = (s0 + s1) + (s2 + s3);
}

// MFMA screening + exact refine.
// Block = 4 waves; wave w handles tokens [tok0,tok0+16) x codes [w*512,(w+1)*512).
// Phase 1: 16x16x32 bf16 MFMA approx dist^2 -> fp16 in LDS.
// Phase 2: per token, chunk-local min; every code with approx <= min + 2*margin
//          gets the EXACT fp32 distance (bit-identical chains to the validated
//          R3-R6 kernel) and a u64-key atomicMin. Margin bound guarantees the
//          true argmin is refined; atomicMin reproduces argmax tie semantics.
__global__ __launch_bounds__(256) void mfma_dist_kernel(
        const float* __restrict__ x, const float* __restrict__ emb,
        const unsigned short* __restrict__ e_bf,
        const float* __restrict__ e2g, const float* __restrict__ x2g,
        const unsigned int* __restrict__ maxe2bits,
        unsigned long long* __restrict__ keys) {
    __shared__ _Float16 approx[4][16][512];  // 64 KB
    int w = threadIdx.x >> 6;
    int lane = threadIdx.x & 63;
    int lm = lane & 15;       // A-row / B-col within tile
    int lq = lane >> 4;       // quad
    int tok0 = blockIdx.x * 16;

    // A fragments: x rows (lane lm -> token tok0+lm), k = lq*8+j (+32)
    const float* xrow = x + (size_t)(tok0 + lm) * D + lq * 8;
    bf16x8 a0, a1;
#pragma unroll
    for (int j = 0; j < 8; ++j) {
        a0[j] = (short)f2bf(xrow[j]);
        a1[j] = (short)f2bf(xrow[32 + j]);
    }
    // x2 for my 4 accumulator rows: token = tok0 + lq*4 + r
    float x2s[4];
#pragma unroll
    for (int r = 0; r < 4; ++r) x2s[r] = x2g[tok0 + lq * 4 + r];

    for (int ct = 0; ct < 32; ++ct) {
        int c0 = w * 512 + ct * 16;
        const unsigned short* eb = e_bf + (size_t)(c0 + lm) * D + lq * 8;
        bf16x8 b0 = *(const bf16x8*)eb;
        bf16x8 b1 = *(const bf16x8*)(eb + 32);
        f32x4 acc = {0.f, 0.f, 0.f, 0.f};
        acc = __builtin_amdgcn_mfma_f32_16x16x32_bf16(a0, b0, acc, 0, 0, 0);
        acc = __builtin_amdgcn_mfma_f32_16x16x32_bf16(a1, b1, acc, 0, 0, 0);
        float e2c = e2g[c0 + lm];
#pragma unroll
        for (int r = 0; r < 4; ++r) {
            float dapp = x2s[r] + e2c - 2.0f * acc[r];
            approx[w][lq * 4 + r][ct * 16 + lm] = (_Float16)dapp;
        }
    }

    float maxn = sqrtf(__uint_as_float(*maxe2bits)) * 1.001f;
    for (int t = 0; t < 16; ++t) {
        h8 hv = *(h8*)&approx[w][t][lane * 8];
        float v[8];
        float m = 3.4e38f;
#pragma unroll
        for (int j = 0; j < 8; ++j) { v[j] = (float)hv[j]; m = fminf(m, v[j]); }
#pragma unroll
        for (int mask = 1; mask < 64; mask <<= 1) m = fminf(m, __shfl_xor(m, mask, 64));
        int tok = tok0 + t;
        float x2v = x2g[tok];
        float marg = 0.006f * sqrtf(x2v) * maxn + 0.4f;
        float thr = m + 2.0f * marg;
#pragma unroll
        for (int j = 0; j < 8; ++j) {
            if (v[j] <= thr) {
                int c = w * 512 + lane * 8 + j;
                // EXACT chains — bit-identical to the validated kernel
                const float4* xr = (const float4*)(x + (size_t)tok * D);
                const float4* er = (const float4*)(emb + (size_t)c * D);
                float d0 = 0.f, d1 = 0.f, d2 = 0.f, d3 = 0.f;
#pragma unroll
                for (int i = 0; i < D / 4; ++i) {
                    float4 xq = xr[i];
                    float4 e = er[i];
                    d0 = fmaf(xq.x, e.x, d0);
                    d1 = fmaf(xq.y, e.y, d1);
                    d2 = fmaf(xq.z, e.z, d2);
                    d3 = fmaf(xq.w, e.w, d3);
                }
                float dot = (d0 + d1) + (d2 + d3);
                float dist2 = x2v + e2g[c] - 2.0f * dot;
                dist2 = fmaxf(dist2, 0.0f);
                unsigned long long key =
                    ((unsigned long long)__float_as_uint(dist2) << 32) | (unsigned int)c;
                atomicMin(&keys[tok], key);
            }
        }
    }
}

__global__ void finalize_kernel(const unsigned long long* __restrict__ keys,
                                int* __restrict__ idx, float* __restrict__ out,
                                float* __restrict__ counts) {
    __shared__ float lcount[C_CODES];
    for (int i = threadIdx.x; i < C_CODES; i += blockDim.x) lcount[i] = 0.0f;
    __syncthreads();
    int n = blockIdx.x * blockDim.x + threadIdx.x;
    int c = (int)(unsigned int)(keys[n] & 0xffffffffull);
    idx[n] = c;
    out[OUT_IND + n] = (float)c;
    atomicAdd(&lcount[c], 1.0f);
    __syncthreads();
    for (int i = threadIdx.x; i < C_CODES; i += blockDim.x) {
        float v = lcount[i];
        if (v != 0.0f) atomicAdd(&counts[i], v);
    }
}

// quantize gather: 16 threads per token, one float4 each.
__global__ void gather_kernel(const float* __restrict__ emb,
                              const int* __restrict__ idx,
                              float* __restrict__ out) {
    int g = blockIdx.x * blockDim.x + threadIdx.x;  // [0, N_TOK*16)
    int n = g >> 4;
    int j = g & 15;
    int c = idx[n];
    float4 e = ((const float4*)emb)[c * (D / 4) + j];
    ((float4*)(out + OUT_QUANT))[g] = e;
}

// Single block: EMA cluster-size + laplace smoothing + exclusive prefix sum.
__global__ void prefix_ema_kernel(const float* __restrict__ counts,
                                  const float* __restrict__ cluster_size,
                                  float* __restrict__ out,
                                  float* __restrict__ smoothed,
                                  int* __restrict__ cursor) {
    __shared__ float scan[256];
    __shared__ float red[256];
    int t = threadIdx.x;
    int base = t * 8;
    float cnt[8], ncs[8];
    float csum = 0.f, nsum = 0.f;
#pragma unroll
    for (int j = 0; j < 8; ++j) {
        cnt[j] = counts[base + j];
        csum += cnt[j];
        ncs[j] = cluster_size[base + j] * DECAYF + cnt[j] * OMDF;
        nsum += ncs[j];
        out[OUT_CS + base + j] = ncs[j];
    }
    scan[t] = csum;
    red[t] = nsum;
    __syncthreads();
    for (int s = 1; s < 256; s <<= 1) {
        float v = scan[t];
        float w = (t >= s) ? scan[t - s] : 0.f;
        __syncthreads();
        scan[t] = v + w;
        __syncthreads();
    }
    for (int s = 128; s > 0; s >>= 1) {
        if (t < s) red[t] += red[t + s];
        __syncthreads();
    }
    float tot = red[0];
    float run = (t == 0) ? 0.f : scan[t - 1];
#pragma unroll
    for (int j = 0; j < 8; ++j) {
        cursor[base + j] = (int)run;  // counts are small ints in float: exact
        run += cnt[j];
        smoothed[base + j] = (ncs[j] + EPSF) / (tot + (float)C_CODES * EPSF) * tot;
    }
}

// counting-sort position scatter; entry packs (code<<16 | token).
__global__ void scatter_pos_kernel(const int* __restrict__ idx,
                                   int* __restrict__ cursor,
                                   unsigned int* __restrict__ sorted) {
    int n = blockIdx.x * blockDim.x + threadIdx.x;
    int c = idx[n];
    int pos = atomicAdd(&cursor[c], 1);
    sorted[pos] = ((unsigned int)c << 16) | (unsigned int)n;
}

// Segmented sum over sorted positions (skew-immune).
__global__ __launch_bounds__(256) void seg_sum_kernel(
        const float* __restrict__ x, const unsigned int* __restrict__ sorted,
        float* __restrict__ embed_sum) {
    int lane = threadIdx.x & 63;
    int q = blockIdx.x * 4 + (threadIdx.x >> 6);  // wave id
    int p0 = q * SEG;

    unsigned int mine = (lane < SEG) ? sorted[p0 + lane] : 0u;
    unsigned int pk[SEG];
#pragma unroll
    for (int j = 0; j < SEG; ++j) pk[j] = __shfl(mine, j, 64);

    float xv[SEG];
#pragma unroll
    for (int j = 0; j < SEG; ++j)
        xv[j] = x[(size_t)(pk[j] & 0xffffu) * D + lane];

    unsigned int run_c = 0xffffffffu;
    float sum = 0.f;
#pragma unroll
    for (int j = 0; j < SEG; ++j) {
        unsigned int c = pk[j] >> 16;  // wave-uniform
        if (c != run_c) {
            if (run_c != 0xffffffffu)
                atomicAdd(&embed_sum[(size_t)run_c * D + lane], sum);
            run_c = c;
            sum = 0.f;
        }
        sum += xv[j];
    }
    atomicAdd(&embed_sum[(size_t)run_c * D + lane], sum);
}

__global__ void ema_embed_kernel(const float* __restrict__ embed_avg,
                                 const float* __restrict__ embed_sum,
                                 const float* __restrict__ smoothed,
                                 float* __restrict__ out) {
    int g = blockIdx.x * blockDim.x + threadIdx.x;  // [0, C_CODES*16)
    int c = g >> 4;
    float4 ea = ((const float4*)embed_avg)[g];
    float4 es = ((const float4*)embed_sum)[g];
    float4 na;
    na.x = ea.x * DECAYF + es.x * OMDF;
    na.y = ea.y * DECAYF + es.y * OMDF;
    na.z = ea.z * DECAYF + es.z * OMDF;
    na.w = ea.w * DECAYF + es.w * OMDF;
    ((float4*)(out + OUT_EAVG))[g] = na;
    float sm = smoothed[c];
    float4 ne;
    ne.x = na.x / sm;
    ne.y = na.y / sm;
    ne.z = na.z / sm;
    ne.w = na.w / sm;
    ((float4*)(out + OUT_EMB))[g] = ne;
}

extern "C" void kernel_launch(void* const* d_in, const int* in_sizes, int n_in,
                              void* d_out, int out_size, void* d_ws, size_t ws_size,
                              hipStream_t stream) {
    const float* x            = (const float*)d_in[0];  // (16,4096,64)
    const float* emb          = (const float*)d_in[1];  // (1,2048,64)
    const float* cluster_size = (const float*)d_in[2];  // (1,2048)
    const float* embed_avg    = (const float*)d_in[3];  // (1,2048,64)
    float* out = (float*)d_out;

    // workspace layout
    unsigned long long* keys = (unsigned long long*)d_ws;   // 65536 u64 (memset 0xFF)
    unsigned short* e_bf = (unsigned short*)(keys + N_TOK); // 2048*64 ushort = 256 KB
    float* e2        = (float*)(e_bf + (size_t)C_CODES * D);// 2048
    float* x2        = e2 + C_CODES;                        // 65536
    float* counts    = x2 + N_TOK;                          // 2048  } zeroed
    unsigned int* maxe2bits = (unsigned int*)(counts + C_CODES); // 1 } together
    float* embed_sum = (float*)(maxe2bits + 4);             // 131072 } with counts
    float* smoothed  = embed_sum + (size_t)C_CODES * D;     // 2048
    int* cursor      = (int*)(smoothed + C_CODES);          // 2048
    int* idx         = cursor + C_CODES;                    // 65536
    unsigned int* sorted = (unsigned int*)(idx + N_TOK);    // 65536

    hipMemsetAsync(keys, 0xFF, (size_t)N_TOK * 8, stream);
    hipMemsetAsync(counts, 0, (size_t)(C_CODES + 4 + C_CODES * D) * sizeof(float), stream);

    prep_e_kernel<<<C_CODES / 256, 256, 0, stream>>>(emb, e2, e_bf, maxe2bits);
    prep_x2_kernel<<<N_TOK / 256, 256, 0, stream>>>(x, x2);
    mfma_dist_kernel<<<N_TOK / 16, 256, 0, stream>>>(x, emb, e_bf, e2, x2,
                                                     maxe2bits, keys);
    finalize_kernel<<<N_TOK / 256, 256, 0, stream>>>(keys, idx, out, counts);
    gather_kernel<<<(N_TOK * 16) / 256, 256, 0, stream>>>(emb, idx, out);
    prefix_ema_kernel<<<1, 256, 0, stream>>>(counts, cluster_size, out, smoothed, cursor);
    scatter_pos_kernel<<<N_TOK / 256, 256, 0, stream>>>(idx, cursor, sorted);
    seg_sum_kernel<<<(N_TOK / SEG) / 4, 256, 0, stream>>>(x, sorted, embed_sum);
    ema_embed_kernel<<<(C_CODES * 16) / 256, 256, 0, stream>>>(embed_avg, embed_sum,
                                                              smoothed, out);
}